// Round 4
// baseline (610.583 us; speedup 1.0000x reference)
//
#include <hip/hip_runtime.h>
#include <hip/hip_bf16.h>

#define BSz 2
#define Nn 15135
#define Ee 242160
#define F_INc 8
#define Hh 64
#define Ll 4
#define HFCc 256
#define NCc 10
#define EPSg 1e-15f
#define NBLK ((Nn + 255) / 256)   // 60 scan blocks

__device__ __forceinline__ float uf(unsigned u) { return __uint_as_float(u); }
__device__ __forceinline__ unsigned short bs16(float f) {
    unsigned b = __float_as_uint(f);
    return (unsigned short)((b + 0x7FFFu + ((b >> 16) & 1u)) >> 16);
}
__device__ __forceinline__ unsigned packbf(float a, float b) {
    return (unsigned)bs16(a) | ((unsigned)bs16(b) << 16);
}
#define RL(v, f) uf((unsigned)__builtin_amdgcn_readlane((int)__float_as_uint(v), (f)))

// ---- CSR build ----------------------------------------------------------

__global__ void count_kernel(const int* __restrict__ dst, int* __restrict__ cnt) {
    int e = blockIdx.x * blockDim.x + threadIdx.x;
    if (e < Ee) atomicAdd(&cnt[dst[e]], 1);
}

__global__ void scan_local(const int* __restrict__ cnt, int* __restrict__ loc,
                           int* __restrict__ bsum) {
    int tid = threadIdx.x, lane = tid & 63, w = tid >> 6;
    int i = blockIdx.x * 256 + tid;
    __shared__ int ws[4];
    int v = (i < Nn) ? cnt[i] : 0;
    int incl = v;
#pragma unroll
    for (int d = 1; d < 64; d <<= 1) {
        int t = __shfl_up(incl, d, 64);
        if (lane >= d) incl += t;
    }
    if (lane == 63) ws[w] = incl;
    __syncthreads();
    int pre = 0;
    for (int ww = 0; ww < w; ++ww) pre += ws[ww];
    if (i < Nn) loc[i] = pre + incl - v;
    if (tid == 255) bsum[blockIdx.x] = pre + incl;
}

__global__ void scan_tops(int* __restrict__ bsum) {
    int lane = threadIdx.x;
    int v = (lane < NBLK) ? bsum[lane] : 0;
    int incl = v;
#pragma unroll
    for (int d = 1; d < 64; d <<= 1) {
        int t = __shfl_up(incl, d, 64);
        if (lane >= d) incl += t;
    }
    if (lane < NBLK) bsum[lane] = incl - v;
}

__global__ void scan_fix(const int* __restrict__ loc, const int* __restrict__ bsum,
                         int* __restrict__ offs, int* __restrict__ cursor) {
    int i = blockIdx.x * 256 + threadIdx.x;
    if (i < Nn) {
        int o = loc[i] + bsum[blockIdx.x];
        offs[i] = o;
        cursor[i] = o;
    }
    if (i == 0) offs[Nn] = Ee;
}

// x (2,N,8) f32 -> xi[n*8+f] = packed bf16 {b0, b1}
__global__ void interleave_x(const float* __restrict__ x, unsigned* __restrict__ xi) {
    int i = blockIdx.x * 256 + threadIdx.x;
    if (i < Nn * F_INc) xi[i] = packbf(x[i], x[Nn * F_INc + i]);
}

// fill CSR + per-layer gauss arrays gauss[l*E + p]
__global__ void fill_kernel(const int* __restrict__ src, const int* __restrict__ dst,
                            const float* __restrict__ pseudo, int* __restrict__ cursor,
                            int* __restrict__ csr_src, float2* __restrict__ gauss,
                            const float* __restrict__ mu1, const float* __restrict__ sigma1,
                            const float* __restrict__ mus, const float* __restrict__ sigmas) {
    int e = blockIdx.x * blockDim.x + threadIdx.x;
    if (e >= Ee) return;
    int p = atomicAdd(&cursor[dst[e]], 1);
    csr_src[p] = src[e];
    float2 ps = ((const float2*)pseudo)[e];
#pragma unroll
    for (int l = 0; l < Ll; ++l) {
        const float* mu = (l == 0) ? mu1 : mus + (l - 1) * 4;
        const float* sg = (l == 0) ? sigma1 : sigmas + (l - 1) * 4;
        float d00 = ps.x - mu[0], d01 = ps.y - mu[1];
        float d10 = ps.x - mu[2], d11 = ps.y - mu[3];
        float i00 = 1.f / (EPSg + sg[0] * sg[0]);
        float i01 = 1.f / (EPSg + sg[1] * sg[1]);
        float i10 = 1.f / (EPSg + sg[2] * sg[2]);
        float i11 = 1.f / (EPSg + sg[3] * sg[3]);
        float g0 = expf(-0.5f * (d00 * d00 * i00 + d01 * d01 * i01));
        float g1 = expf(-0.5f * (d10 * d10 * i10 + d11 * d11 * i11));
        gauss[(size_t)l * Ee + p] = make_float2(g0, g1);
    }
}

// ---- layer 0: F=8, lane = esub*8+f (8 edges per iteration) ---------------

__global__ __launch_bounds__(512, 4)
void layer0_fused(const unsigned* __restrict__ xi, const int* __restrict__ offs,
                  const int* __restrict__ csr_src, const float2* __restrict__ gauss,
                  const float* __restrict__ G, const float* __restrict__ root,
                  const float* __restrict__ bias, const float* __restrict__ fc_w,
                  unsigned* __restrict__ hout, float* __restrict__ node) {
    __shared__ float sG[F_INc * 128];
    __shared__ float sR[F_INc * 64];
    int tid = threadIdx.x;
    for (int i = tid; i < F_INc * 128; i += 512) sG[i] = G[i];
    for (int i = tid; i < F_INc * 64; i += 512) sR[i] = root[i];
    __syncthreads();
    int lane = tid & 63;
    int n = blockIdx.x * 8 + (tid >> 6);
    if (n >= Nn) return;
    int esub = lane >> 3, f = lane & 7;
    int s0 = offs[n], s1 = offs[n + 1];
    float a00 = 0.f, a10 = 0.f, a01 = 0.f, a11 = 0.f;
    for (int p0 = s0; p0 < s1; p0 += 8) {
        int p = p0 + esub;
        bool v = p < s1;
        int sa = v ? csr_src[p] : 0;
        float2 g = v ? gauss[p] : make_float2(0.f, 0.f);
        unsigned u = xi[sa * F_INc + f];
        float x0 = uf(u << 16), x1 = uf(u & 0xFFFF0000u);
        a00 += g.x * x0; a10 += g.y * x0;
        a01 += g.x * x1; a11 += g.y * x1;
    }
#pragma unroll
    for (int d = 8; d <= 32; d <<= 1) {
        a00 += __shfl_xor(a00, d, 64);
        a10 += __shfl_xor(a10, d, 64);
        a01 += __shfl_xor(a01, d, 64);
        a11 += __shfl_xor(a11, d, 64);
    }
    float dg = (float)(s1 - s0);
    if (dg < 1.f) dg = 1.f;
    float inv = 1.f / dg;
    a00 *= inv; a10 *= inv; a01 *= inv; a11 *= inv;
    unsigned up = xi[n * F_INc + f];
    float pv0 = uf(up << 16), pv1 = uf(up & 0xFFFF0000u);
    float bv = bias[lane];
    float val0 = bv, val1 = bv;
#pragma unroll
    for (int ff = 0; ff < F_INc; ++ff) {
        float G0 = sG[ff * 128 + lane];
        float G1 = sG[ff * 128 + 64 + lane];
        float Rv = sR[ff * 64 + lane];
        val0 = fmaf(RL(a00, ff), G0, val0);
        val0 = fmaf(RL(a10, ff), G1, val0);
        val0 = fmaf(RL(pv0, ff), Rv, val0);
        val1 = fmaf(RL(a01, ff), G0, val1);
        val1 = fmaf(RL(a11, ff), G1, val1);
        val1 = fmaf(RL(pv1, ff), Rv, val1);
    }
    val0 = val0 > 0.f ? val0 : expm1f(val0);
    val1 = val1 > 0.f ? val1 : expm1f(val1);
    hout[(size_t)n * 64 + lane] = packbf(val0, val1);
    float fw = fc_w[lane * Ll + 0];
    float r0 = val0 * fw, r1 = val1 * fw;
#pragma unroll
    for (int off = 32; off; off >>= 1) {
        r0 += __shfl_down(r0, off, 64);
        r1 += __shfl_down(r1, off, 64);
    }
    if (lane == 0) { node[n] = r0; node[Nn + n] = r1; }
}

// ---- layers 1..3: F=64, wave per node ------------------------------------

__global__ __launch_bounds__(512, 6)
void layer_fused(const unsigned* __restrict__ h2, const int* __restrict__ offs,
                 const int* __restrict__ csr_src, const float2* __restrict__ gauss,
                 const float* __restrict__ G, const float* __restrict__ root,
                 const float* __restrict__ bias, const float* __restrict__ fc_w,
                 int l, unsigned* __restrict__ hout, float* __restrict__ node) {
    __shared__ float sG[Hh * 128];   // 32 KB
    __shared__ float sR[Hh * 64];    // 16 KB
    int tid = threadIdx.x;
    {
        const float4* G4 = (const float4*)G;
        const float4* R4 = (const float4*)root;
        float4* sG4 = (float4*)sG;
        float4* sR4 = (float4*)sR;
        for (int i = tid; i < Hh * 32; i += 512) sG4[i] = G4[i];
        for (int i = tid; i < Hh * 16; i += 512) sR4[i] = R4[i];
    }
    __syncthreads();
    int lane = tid & 63;
    int n = blockIdx.x * 8 + (tid >> 6);
    if (n >= Nn) return;
    int s0 = offs[n], s1 = offs[n + 1];
    float a00 = 0.f, a10 = 0.f, a01 = 0.f, a11 = 0.f;
    int p = s0;
    for (; p + 3 < s1; p += 4) {
        int sa = csr_src[p], sb = csr_src[p + 1], sc = csr_src[p + 2], sd = csr_src[p + 3];
        float2 ga = gauss[p], gb = gauss[p + 1], gc = gauss[p + 2], gd = gauss[p + 3];
        unsigned ua = h2[(size_t)sa * 64 + lane];
        unsigned ub = h2[(size_t)sb * 64 + lane];
        unsigned uc = h2[(size_t)sc * 64 + lane];
        unsigned ud = h2[(size_t)sd * 64 + lane];
        float va0 = uf(ua << 16), va1 = uf(ua & 0xFFFF0000u);
        float vb0 = uf(ub << 16), vb1 = uf(ub & 0xFFFF0000u);
        float vc0 = uf(uc << 16), vc1 = uf(uc & 0xFFFF0000u);
        float vd0 = uf(ud << 16), vd1 = uf(ud & 0xFFFF0000u);
        a00 += ga.x * va0 + gb.x * vb0 + gc.x * vc0 + gd.x * vd0;
        a10 += ga.y * va0 + gb.y * vb0 + gc.y * vc0 + gd.y * vd0;
        a01 += ga.x * va1 + gb.x * vb1 + gc.x * vc1 + gd.x * vd1;
        a11 += ga.y * va1 + gb.y * vb1 + gc.y * vc1 + gd.y * vd1;
    }
    for (; p < s1; ++p) {
        int sa = csr_src[p];
        float2 ga = gauss[p];
        unsigned ua = h2[(size_t)sa * 64 + lane];
        float va0 = uf(ua << 16), va1 = uf(ua & 0xFFFF0000u);
        a00 += ga.x * va0; a10 += ga.y * va0;
        a01 += ga.x * va1; a11 += ga.y * va1;
    }
    float dg = (float)(s1 - s0);
    if (dg < 1.f) dg = 1.f;
    float inv = 1.f / dg;
    a00 *= inv; a10 *= inv; a01 *= inv; a11 *= inv;
    unsigned up = h2[(size_t)n * 64 + lane];
    float pv0 = uf(up << 16), pv1 = uf(up & 0xFFFF0000u);
    float bv = bias[lane];
    float val0 = bv, val1 = bv;
#pragma unroll
    for (int f = 0; f < Hh; ++f) {
        float G0 = sG[f * 128 + lane];
        float G1 = sG[f * 128 + 64 + lane];
        float Rv = sR[f * 64 + lane];
        val0 = fmaf(RL(a00, f), G0, val0);
        val0 = fmaf(RL(a10, f), G1, val0);
        val0 = fmaf(RL(pv0, f), Rv, val0);
        val1 = fmaf(RL(a01, f), G0, val1);
        val1 = fmaf(RL(a11, f), G1, val1);
        val1 = fmaf(RL(pv1, f), Rv, val1);
    }
    val0 = val0 > 0.f ? val0 : expm1f(val0);
    val1 = val1 > 0.f ? val1 : expm1f(val1);
    hout[(size_t)n * 64 + lane] = packbf(val0, val1);
    float fw = fc_w[lane * Ll + l];
    float r0 = val0 * fw, r1 = val1 * fw;
#pragma unroll
    for (int off = 32; off; off >>= 1) {
        r0 += __shfl_down(r0, off, 64);
        r1 += __shfl_down(r1, off, 64);
    }
    if (lane == 0) { node[n] += r0; node[Nn + n] += r1; }
}

// ---- head ----------------------------------------------------------------

__global__ void lin1_kernel(const float* __restrict__ node, const float* __restrict__ w,
                            const float* __restrict__ fcb, float* __restrict__ h1acc) {
    int hfc = threadIdx.x;
    int n0 = blockIdx.x * 64;
    int nend = n0 + 64 < Nn ? n0 + 64 : Nn;
    float fb = fcb[0];
    float a0 = 0.f, a1 = 0.f;
    for (int n = n0; n < nend; ++n) {
        float wv = w[(size_t)n * HFCc + hfc];
        a0 += (node[n] + fb) * wv;
        a1 += (node[Nn + n] + fb) * wv;
    }
    atomicAdd(&h1acc[hfc], a0);
    atomicAdd(&h1acc[HFCc + hfc], a1);
}

__global__ void head_kernel(const float* __restrict__ h1acc, const float* __restrict__ l1b,
                            const float* __restrict__ w2, const float* __restrict__ b2,
                            float* __restrict__ out) {
    __shared__ float sh[HFCc];
    __shared__ float slog[NCc];
    __shared__ float s_lse;
    int tid = threadIdx.x;
    for (int b = 0; b < BSz; ++b) {
        float v = h1acc[b * HFCc + tid] + l1b[tid];
        v = v > 0.f ? v : expm1f(v);
        sh[tid] = v;
        __syncthreads();
        if (tid < NCc) {
            float s = b2[tid];
            for (int i = 0; i < HFCc; ++i) s += sh[i] * w2[i * NCc + tid];
            slog[tid] = s;
        }
        __syncthreads();
        if (tid == 0) {
            float m = slog[0];
            for (int c = 1; c < NCc; ++c) m = fmaxf(m, slog[c]);
            float se = 0.f;
            for (int c = 0; c < NCc; ++c) se += expf(slog[c] - m);
            s_lse = m + logf(se);
        }
        __syncthreads();
        if (tid < NCc) out[b * NCc + tid] = slog[tid] - s_lse;
        __syncthreads();
    }
}

extern "C" void kernel_launch(void* const* d_in, const int* in_sizes, int n_in,
                              void* d_out, int out_size, void* d_ws, size_t ws_size,
                              hipStream_t stream) {
    const float* x      = (const float*)d_in[0];
    const int*   ei     = (const int*)d_in[2];
    const float* pseudo = (const float*)d_in[3];
    const float* g1     = (const float*)d_in[4];
    const float* mu1    = (const float*)d_in[5];
    const float* sigma1 = (const float*)d_in[6];
    const float* root1  = (const float*)d_in[7];
    const float* b1     = (const float*)d_in[8];
    const float* gs     = (const float*)d_in[9];
    const float* mus    = (const float*)d_in[10];
    const float* sigmas = (const float*)d_in[11];
    const float* roots  = (const float*)d_in[12];
    const float* bs_p   = (const float*)d_in[13];
    const float* fc_w   = (const float*)d_in[14];
    const float* fc_b   = (const float*)d_in[15];
    const float* lin1_w = (const float*)d_in[16];
    const float* lin1_b = (const float*)d_in[17];
    const float* lin2_w = (const float*)d_in[18];
    const float* lin2_b = (const float*)d_in[19];
    float* out = (float*)d_out;

    const int* src = ei;
    const int* dst = ei + Ee;

    auto alignup = [](size_t v) { return (v + 255) & ~(size_t)255; };
    char* ws = (char*)d_ws;
    size_t off = 0;
    float*    node    = (float*)(ws + off);    off += alignup((size_t)BSz * Nn * 4);
    float*    h1acc   = (float*)(ws + off);    off += alignup((size_t)BSz * HFCc * 4);
    int*      offs    = (int*)(ws + off);      off += alignup((size_t)(Nn + 1) * 4);
    int*      cursor  = (int*)(ws + off);      off += alignup((size_t)Nn * 4);
    int*      loc     = (int*)(ws + off);      off += alignup((size_t)Nn * 4);
    int*      bsum    = (int*)(ws + off);      off += alignup((size_t)64 * 4);
    int*      csr_src = (int*)(ws + off);      off += alignup((size_t)Ee * 4);
    float2*   gauss   = (float2*)(ws + off);   off += alignup((size_t)Ll * Ee * 8);
    unsigned* xi      = (unsigned*)(ws + off); off += alignup((size_t)Nn * F_INc * 4);
    unsigned* hA      = (unsigned*)(ws + off); off += alignup((size_t)Nn * 64 * 4);
    unsigned* hB      = (unsigned*)(ws + off); off += alignup((size_t)Nn * 64 * 4);
    (void)ws_size; (void)in_sizes; (void)n_in; (void)out_size;

    hipMemsetAsync(cursor, 0, (size_t)Nn * 4, stream);
    hipMemsetAsync(h1acc, 0, (size_t)BSz * HFCc * 4, stream);

    count_kernel<<<(Ee + 255) / 256, 256, 0, stream>>>(dst, cursor);
    scan_local<<<NBLK, 256, 0, stream>>>(cursor, loc, bsum);
    scan_tops<<<1, 64, 0, stream>>>(bsum);
    scan_fix<<<NBLK, 256, 0, stream>>>(loc, bsum, offs, cursor);
    interleave_x<<<(Nn * F_INc + 255) / 256, 256, 0, stream>>>(x, xi);
    fill_kernel<<<(Ee + 255) / 256, 256, 0, stream>>>(src, dst, pseudo, cursor, csr_src, gauss,
                                                      mu1, sigma1, mus, sigmas);

    int lgrid = (Nn + 7) / 8;
    layer0_fused<<<lgrid, 512, 0, stream>>>(xi, offs, csr_src, gauss, g1, root1, b1, fc_w,
                                            hA, node);
    unsigned* prev = hA;
    unsigned* next = hB;
    for (int l = 1; l < Ll; ++l) {
        const float* G  = gs    + (size_t)(l - 1) * Hh * 128;
        const float* rt = roots + (size_t)(l - 1) * Hh * Hh;
        const float* bb = bs_p  + (size_t)(l - 1) * Hh;
        layer_fused<<<lgrid, 512, 0, stream>>>(prev, offs, csr_src, gauss + (size_t)l * Ee,
                                               G, rt, bb, fc_w, l, next, node);
        unsigned* t = prev; prev = next; next = t;
    }

    lin1_kernel<<<(Nn + 63) / 64, 256, 0, stream>>>(node, lin1_w, fc_b, h1acc);
    head_kernel<<<1, HFCc, 0, stream>>>(h1acc, lin1_b, lin2_w, lin2_b, out);
}

// Round 5
// 351.162 us; speedup vs baseline: 1.7387x; 1.7387x over previous
//
#include <hip/hip_runtime.h>
#include <hip/hip_bf16.h>

#define BSz 2
#define Nn 15135
#define Ee 242160
#define F_INc 8
#define Hh 64
#define Ll 4
#define HFCc 256
#define NCc 10
#define EPSg 1e-15f
#define NBLK ((Nn + 255) / 256)   // 60 scan blocks

__device__ __forceinline__ float uf(unsigned u) { return __uint_as_float(u); }
__device__ __forceinline__ unsigned short bs16(float f) {
    unsigned b = __float_as_uint(f);
    return (unsigned short)((b + 0x7FFFu + ((b >> 16) & 1u)) >> 16);
}
__device__ __forceinline__ unsigned packbf(float a, float b) {
    return (unsigned)bs16(a) | ((unsigned)bs16(b) << 16);
}

// ---- CSR build ----------------------------------------------------------

__global__ void count_kernel(const int* __restrict__ dst, int* __restrict__ cnt) {
    int e = blockIdx.x * blockDim.x + threadIdx.x;
    if (e < Ee) atomicAdd(&cnt[dst[e]], 1);
}

__global__ void scan_local(const int* __restrict__ cnt, int* __restrict__ loc,
                           int* __restrict__ bsum) {
    int tid = threadIdx.x, lane = tid & 63, w = tid >> 6;
    int i = blockIdx.x * 256 + tid;
    __shared__ int ws[4];
    int v = (i < Nn) ? cnt[i] : 0;
    int incl = v;
#pragma unroll
    for (int d = 1; d < 64; d <<= 1) {
        int t = __shfl_up(incl, d, 64);
        if (lane >= d) incl += t;
    }
    if (lane == 63) ws[w] = incl;
    __syncthreads();
    int pre = 0;
    for (int ww = 0; ww < w; ++ww) pre += ws[ww];
    if (i < Nn) loc[i] = pre + incl - v;
    if (tid == 255) bsum[blockIdx.x] = pre + incl;
}

__global__ void scan_tops(int* __restrict__ bsum) {
    int lane = threadIdx.x;
    int v = (lane < NBLK) ? bsum[lane] : 0;
    int incl = v;
#pragma unroll
    for (int d = 1; d < 64; d <<= 1) {
        int t = __shfl_up(incl, d, 64);
        if (lane >= d) incl += t;
    }
    if (lane < NBLK) bsum[lane] = incl - v;
}

__global__ void scan_fix(const int* __restrict__ loc, const int* __restrict__ bsum,
                         int* __restrict__ offs, int* __restrict__ cursor) {
    int i = blockIdx.x * 256 + threadIdx.x;
    if (i < Nn) {
        int o = loc[i] + bsum[blockIdx.x];
        offs[i] = o;
        cursor[i] = o;
    }
    if (i == 0) offs[Nn] = Ee;
}

// fill CSR + per-layer gauss arrays gauss[l*E + p] (contiguous per layer)
__global__ void fill_kernel(const int* __restrict__ src, const int* __restrict__ dst,
                            const float* __restrict__ pseudo, int* __restrict__ cursor,
                            int* __restrict__ csr_src, float2* __restrict__ gauss,
                            const float* __restrict__ mu1, const float* __restrict__ sigma1,
                            const float* __restrict__ mus, const float* __restrict__ sigmas) {
    int e = blockIdx.x * blockDim.x + threadIdx.x;
    if (e >= Ee) return;
    int p = atomicAdd(&cursor[dst[e]], 1);
    csr_src[p] = src[e];
    float2 ps = ((const float2*)pseudo)[e];
#pragma unroll
    for (int l = 0; l < Ll; ++l) {
        const float* mu = (l == 0) ? mu1 : mus + (l - 1) * 4;
        const float* sg = (l == 0) ? sigma1 : sigmas + (l - 1) * 4;
        float d00 = ps.x - mu[0], d01 = ps.y - mu[1];
        float d10 = ps.x - mu[2], d11 = ps.y - mu[3];
        float i00 = 1.f / (EPSg + sg[0] * sg[0]);
        float i01 = 1.f / (EPSg + sg[1] * sg[1]);
        float i10 = 1.f / (EPSg + sg[2] * sg[2]);
        float i11 = 1.f / (EPSg + sg[3] * sg[3]);
        float g0 = expf(-0.5f * (d00 * d00 * i00 + d01 * d01 * i01));
        float g1 = expf(-0.5f * (d10 * d10 * i10 + d11 * d11 * i11));
        gauss[(size_t)l * Ee + p] = make_float2(g0, g1);
    }
}

// ---- transform: hkp[n][h] = uint2{pack(b0k0,b1k0), pack(b0k1,b1k1)} ------
// block = 4 nodes x 64 channels; both batches per thread.
template<int F>
__global__ void transform_pack(const float* __restrict__ in, const float* __restrict__ g,
                               uint2* __restrict__ hkp) {
    int tid = threadIdx.x;
    int h = tid & 63;
    int r = tid >> 6;
    int n0 = blockIdx.x * 4;
    int n = n0 + r;
    __shared__ float s_in[4][2][F];
    for (int idx = tid; idx < 4 * 2 * F; idx += 256) {
        int rr = idx / (2 * F);
        int bb = (idx / F) & 1;
        int ff = idx % F;
        int gn = n0 + rr;
        s_in[rr][bb][ff] = (gn < Nn) ? in[((size_t)bb * Nn + gn) * F + ff] : 0.f;
    }
    __syncthreads();
    if (n >= Nn) return;
    float a00 = 0.f, a01 = 0.f, a10 = 0.f, a11 = 0.f;  // a{batch}{k}
#pragma unroll
    for (int f = 0; f < F; ++f) {
        float G0 = g[f * 128 + h];
        float G1 = g[f * 128 + 64 + h];
        float v0 = s_in[r][0][f];
        float v1 = s_in[r][1][f];
        a00 = fmaf(v0, G0, a00);
        a01 = fmaf(v0, G1, a01);
        a10 = fmaf(v1, G0, a10);
        a11 = fmaf(v1, G1, a11);
    }
    hkp[(size_t)n * 64 + h] = make_uint2(packbf(a00, a10), packbf(a01, a11));
}

// ---- gather + combine: one wave per node, both batches -------------------
template<int F>
__global__ void gather_combine(const uint2* __restrict__ hkp, const int* __restrict__ offs,
                               const int* __restrict__ csr_src, const float2* __restrict__ gauss,
                               const float* __restrict__ prev, const float* __restrict__ root,
                               const float* __restrict__ bias, const float* __restrict__ fc_w,
                               int l, float* __restrict__ hout, float* __restrict__ node) {
    int tid = threadIdx.x;
    int lane = tid & 63;
    int n = blockIdx.x * 4 + (tid >> 6);
    if (n >= Nn) return;
    int s0 = offs[n], s1 = offs[n + 1];
    float acc0 = 0.f, acc1 = 0.f;
    int p = s0;
    for (; p + 3 < s1; p += 4) {
        int sa = csr_src[p], sb = csr_src[p + 1], sc = csr_src[p + 2], sd = csr_src[p + 3];
        float2 ga = gauss[p], gb = gauss[p + 1], gc = gauss[p + 2], gd = gauss[p + 3];
        uint2 ua = hkp[(size_t)sa * 64 + lane];
        uint2 ub = hkp[(size_t)sb * 64 + lane];
        uint2 uc = hkp[(size_t)sc * 64 + lane];
        uint2 ud = hkp[(size_t)sd * 64 + lane];
        acc0 += ga.x * uf(ua.x << 16) + ga.y * uf(ua.y << 16);
        acc1 += ga.x * uf(ua.x & 0xFFFF0000u) + ga.y * uf(ua.y & 0xFFFF0000u);
        acc0 += gb.x * uf(ub.x << 16) + gb.y * uf(ub.y << 16);
        acc1 += gb.x * uf(ub.x & 0xFFFF0000u) + gb.y * uf(ub.y & 0xFFFF0000u);
        acc0 += gc.x * uf(uc.x << 16) + gc.y * uf(uc.y << 16);
        acc1 += gc.x * uf(uc.x & 0xFFFF0000u) + gc.y * uf(uc.y & 0xFFFF0000u);
        acc0 += gd.x * uf(ud.x << 16) + gd.y * uf(ud.y << 16);
        acc1 += gd.x * uf(ud.x & 0xFFFF0000u) + gd.y * uf(ud.y & 0xFFFF0000u);
    }
    for (; p < s1; ++p) {
        int sa = csr_src[p];
        float2 ga = gauss[p];
        uint2 ua = hkp[(size_t)sa * 64 + lane];
        acc0 += ga.x * uf(ua.x << 16) + ga.y * uf(ua.y << 16);
        acc1 += ga.x * uf(ua.x & 0xFFFF0000u) + ga.y * uf(ua.y & 0xFFFF0000u);
    }
    float dg = (float)(s1 - s0);
    if (dg < 1.f) dg = 1.f;
    float inv = 1.f / dg;
    float bv = bias[lane];
    float fw = fc_w[lane * Ll + l];
#pragma unroll
    for (int b = 0; b < BSz; ++b) {
        size_t row = (size_t)b * Nn + n;
        float val = (b == 0 ? acc0 : acc1) * inv;
        float rsum = 0.f;
#pragma unroll
        for (int f = 0; f < F; ++f) rsum += prev[row * F + f] * root[f * 64 + lane];
        val += rsum + bv;
        val = val > 0.f ? val : expm1f(val);
        hout[row * 64 + lane] = val;
        float r = val * fw;
#pragma unroll
        for (int off = 32; off; off >>= 1) r += __shfl_down(r, off, 64);
        if (lane == 0) node[row] = (l == 0) ? r : node[row] + r;
    }
}

// ---- head ----------------------------------------------------------------

__global__ void lin1_kernel(const float* __restrict__ node, const float* __restrict__ w,
                            const float* __restrict__ fcb, float* __restrict__ h1acc) {
    int hfc = threadIdx.x;
    int n0 = blockIdx.x * 64;
    int nend = n0 + 64 < Nn ? n0 + 64 : Nn;
    float fb = fcb[0];
    float a0 = 0.f, a1 = 0.f;
    for (int n = n0; n < nend; ++n) {
        float wv = w[(size_t)n * HFCc + hfc];
        a0 += (node[n] + fb) * wv;
        a1 += (node[Nn + n] + fb) * wv;
    }
    atomicAdd(&h1acc[hfc], a0);
    atomicAdd(&h1acc[HFCc + hfc], a1);
}

__global__ void head_kernel(const float* __restrict__ h1acc, const float* __restrict__ l1b,
                            const float* __restrict__ w2, const float* __restrict__ b2,
                            float* __restrict__ out) {
    __shared__ float sh[HFCc];
    __shared__ float slog[NCc];
    __shared__ float s_lse;
    int tid = threadIdx.x;
    for (int b = 0; b < BSz; ++b) {
        float v = h1acc[b * HFCc + tid] + l1b[tid];
        v = v > 0.f ? v : expm1f(v);
        sh[tid] = v;
        __syncthreads();
        if (tid < NCc) {
            float s = b2[tid];
            for (int i = 0; i < HFCc; ++i) s += sh[i] * w2[i * NCc + tid];
            slog[tid] = s;
        }
        __syncthreads();
        if (tid == 0) {
            float m = slog[0];
            for (int c = 1; c < NCc; ++c) m = fmaxf(m, slog[c]);
            float se = 0.f;
            for (int c = 0; c < NCc; ++c) se += expf(slog[c] - m);
            s_lse = m + logf(se);
        }
        __syncthreads();
        if (tid < NCc) out[b * NCc + tid] = slog[tid] - s_lse;
        __syncthreads();
    }
}

extern "C" void kernel_launch(void* const* d_in, const int* in_sizes, int n_in,
                              void* d_out, int out_size, void* d_ws, size_t ws_size,
                              hipStream_t stream) {
    const float* x      = (const float*)d_in[0];
    const int*   ei     = (const int*)d_in[2];
    const float* pseudo = (const float*)d_in[3];
    const float* g1     = (const float*)d_in[4];
    const float* mu1    = (const float*)d_in[5];
    const float* sigma1 = (const float*)d_in[6];
    const float* root1  = (const float*)d_in[7];
    const float* b1     = (const float*)d_in[8];
    const float* gs     = (const float*)d_in[9];
    const float* mus    = (const float*)d_in[10];
    const float* sigmas = (const float*)d_in[11];
    const float* roots  = (const float*)d_in[12];
    const float* bs_p   = (const float*)d_in[13];
    const float* fc_w   = (const float*)d_in[14];
    const float* fc_b   = (const float*)d_in[15];
    const float* lin1_w = (const float*)d_in[16];
    const float* lin1_b = (const float*)d_in[17];
    const float* lin2_w = (const float*)d_in[18];
    const float* lin2_b = (const float*)d_in[19];
    float* out = (float*)d_out;

    const int* src = ei;
    const int* dst = ei + Ee;

    auto alignup = [](size_t v) { return (v + 255) & ~(size_t)255; };
    char* ws = (char*)d_ws;
    size_t off = 0;
    float*  node    = (float*)(ws + off);   off += alignup((size_t)BSz * Nn * 4);
    float*  h1acc   = (float*)(ws + off);   off += alignup((size_t)BSz * HFCc * 4);
    int*    offs    = (int*)(ws + off);     off += alignup((size_t)(Nn + 1) * 4);
    int*    cursor  = (int*)(ws + off);     off += alignup((size_t)Nn * 4);
    int*    loc     = (int*)(ws + off);     off += alignup((size_t)Nn * 4);
    int*    bsum    = (int*)(ws + off);     off += alignup((size_t)64 * 4);
    int*    csr_src = (int*)(ws + off);     off += alignup((size_t)Ee * 4);
    float2* gauss   = (float2*)(ws + off);  off += alignup((size_t)Ll * Ee * 8);
    uint2*  hkp     = (uint2*)(ws + off);   off += alignup((size_t)Nn * 64 * 8);
    float*  hA      = (float*)(ws + off);   off += alignup((size_t)BSz * Nn * 64 * 4);
    float*  hB      = (float*)(ws + off);   off += alignup((size_t)BSz * Nn * 64 * 4);
    (void)ws_size; (void)in_sizes; (void)n_in; (void)out_size;

    hipMemsetAsync(cursor, 0, (size_t)Nn * 4, stream);
    hipMemsetAsync(h1acc, 0, (size_t)BSz * HFCc * 4, stream);

    count_kernel<<<(Ee + 255) / 256, 256, 0, stream>>>(dst, cursor);
    scan_local<<<NBLK, 256, 0, stream>>>(cursor, loc, bsum);
    scan_tops<<<1, 64, 0, stream>>>(bsum);
    scan_fix<<<NBLK, 256, 0, stream>>>(loc, bsum, offs, cursor);
    fill_kernel<<<(Ee + 255) / 256, 256, 0, stream>>>(src, dst, pseudo, cursor, csr_src, gauss,
                                                      mu1, sigma1, mus, sigmas);

    const float* prev = x;
    float* hnxt = hA;
    float* hother = hB;
    int ngrid = (Nn + 3) / 4;
    for (int l = 0; l < Ll; ++l) {
        const float* g  = (l == 0) ? g1    : gs    + (size_t)(l - 1) * Hh * 128;
        const float* rt = (l == 0) ? root1 : roots + (size_t)(l - 1) * Hh * Hh;
        const float* bb = (l == 0) ? b1    : bs_p  + (size_t)(l - 1) * Hh;

        if (l == 0)
            transform_pack<F_INc><<<ngrid, 256, 0, stream>>>(prev, g, hkp);
        else
            transform_pack<Hh><<<ngrid, 256, 0, stream>>>(prev, g, hkp);

        if (l == 0)
            gather_combine<F_INc><<<ngrid, 256, 0, stream>>>(hkp, offs, csr_src,
                gauss + (size_t)l * Ee, prev, rt, bb, fc_w, l, hnxt, node);
        else
            gather_combine<Hh><<<ngrid, 256, 0, stream>>>(hkp, offs, csr_src,
                gauss + (size_t)l * Ee, prev, rt, bb, fc_w, l, hnxt, node);

        prev = hnxt;
        float* tmp = hnxt; hnxt = hother; hother = tmp;
    }

    lin1_kernel<<<(Nn + 63) / 64, 256, 0, stream>>>(node, lin1_w, fc_b, h1acc);
    head_kernel<<<1, HFCc, 0, stream>>>(h1acc, lin1_b, lin2_w, lin2_b, out);
}